// Round 5
// baseline (365.021 us; speedup 1.0000x reference)
//
#include <hip/hip_runtime.h>
#include <hip/hip_bf16.h>
#include <math.h>

// Transformer block B=2 T=2048 C=1024 H=16 HS=64.
// R5: attention parallelism rewrite. Column-softmax (query-axis softmax quirk)
// with fixed stabilizer folded away (exp2-only path, Q pre-scaled by
// 0.125*log2e in QKV-GEMM epilogue).
//  - stats: 16 k-rows per 1-wave block, q split in 1024-chunks -> partial
//    sums sp0/sp1, reduced inline in transpose_v (dinv folded into V').
//  - pv: 16 q-rows per 1-wave block, k split in 1024-chunks -> f32 partials
//    (part0 in y region, part1 in hb region - both dead during attention),
//    reduced by att_reduce into bf16 att (placed in dead Q region).
//  - ping-pong register prefetch of K/V tiles inside the k-loop.

#define B_   2
#define T_   2048
#define C_   1024
#define H_   16
#define HS_  64
#define NROWS 4096
#define C3   3072
#define K1C  0.1803368801111244f    // 0.125 * log2(e), folded into Q

typedef unsigned short ushort_t;
typedef __attribute__((ext_vector_type(8))) short short8;
typedef __attribute__((ext_vector_type(4))) float f32x4;

__device__ __forceinline__ ushort_t f2bf(float f) {
  __hip_bfloat16 h = __float2bfloat16(f);
  ushort_t u; __builtin_memcpy(&u, &h, 2); return u;
}
__device__ __forceinline__ float bf2f(ushort_t u) {
  union { unsigned u; float f; } v; v.u = ((unsigned)u) << 16;
  return v.f;
}
__device__ __forceinline__ unsigned pk2(float a, float b) {
  __hip_bfloat162 t = __float22bfloat162_rn(make_float2(a, b));
  unsigned u; __builtin_memcpy(&u, &t, 4); return u;
}
__device__ __forceinline__ f32x4 mfma16(short8 a, short8 b, f32x4 c) {
  return __builtin_amdgcn_mfma_f32_16x16x32_bf16(a, b, c, 0, 0, 0);
}
typedef const __attribute__((address_space(1))) void g_void;
typedef __attribute__((address_space(3))) void l_void;
__device__ __forceinline__ void gl_lds16(const void* g, void* l) {
  __builtin_amdgcn_global_load_lds((g_void*)g, (l_void*)l, 16, 0, 0);
}

// ---------------- LayerNorm (f32 in -> bf16 out) ----------------
__global__ __launch_bounds__(256) void ln_bf16(
    const float* __restrict__ x, const float* __restrict__ g,
    const float* __restrict__ b, ushort_t* __restrict__ out) {
  int row = blockIdx.x;
  const float* xr = x + (size_t)row * C_;
  int t = threadIdx.x;
  float4 v = ((const float4*)xr)[t];
  float s  = v.x + v.y + v.z + v.w;
  float ss = v.x*v.x + v.y*v.y + v.z*v.z + v.w*v.w;
  #pragma unroll
  for (int off = 32; off > 0; off >>= 1) {
    s  += __shfl_down(s, off);
    ss += __shfl_down(ss, off);
  }
  __shared__ float red[2][4];
  int wid = t >> 6, lane = t & 63;
  if (lane == 0) { red[0][wid] = s; red[1][wid] = ss; }
  __syncthreads();
  if (t == 0) {
    float a = 0, c = 0;
    for (int i = 0; i < 4; i++) { a += red[0][i]; c += red[1][i]; }
    red[0][0] = a; red[1][0] = c;
  }
  __syncthreads();
  float mean = red[0][0] * (1.0f / C_);
  float var  = red[1][0] * (1.0f / C_) - mean * mean;
  float r = rsqrtf(var + 1e-5f);
  float4 gv = ((const float4*)g)[t];
  float4 bv = ((const float4*)b)[t];
  ushort4 o;
  o.x = f2bf((v.x - mean) * r * gv.x + bv.x);
  o.y = f2bf((v.y - mean) * r * gv.y + bv.y);
  o.z = f2bf((v.z - mean) * r * gv.z + bv.z);
  o.w = f2bf((v.w - mean) * r * gv.w + bv.w);
  ((ushort4*)(out + (size_t)row * C_))[t] = o;
}

// ---- Wq,Wk,Wv (H,C,HS) f32 -> concatenated (3072, 1024) bf16 N-major ----
__global__ __launch_bounds__(256) void conv_wqkv3(
    const float* __restrict__ Wq, const float* __restrict__ Wk,
    const float* __restrict__ Wv, ushort_t* __restrict__ Wt) {
  int idx = blockIdx.x * 256 + threadIdx.x;
  int n = idx >> 10, c = idx & 1023;
  int sel = n >> 10, nn = n & 1023;
  const float* W = (sel == 0) ? Wq : ((sel == 1) ? Wk : Wv);
  Wt[idx] = f2bf(W[((size_t)(nn >> 6) * C_ + c) * HS_ + (nn & 63)]);
}

// ---- Wo,W1,W2 (K,N) f32 -> three contiguous (N,K) bf16 blocks ----
__global__ __launch_bounds__(256) void conv_wt3(
    const float* __restrict__ W0, const float* __restrict__ W1,
    const float* __restrict__ W2, ushort_t* __restrict__ Wt) {
  int idx = blockIdx.x * 256 + threadIdx.x;
  int sel = idx >> 20, rem = idx & 1048575;
  int n = rem >> 10, k = rem & 1023;
  const float* W = (sel == 0) ? W0 : ((sel == 1) ? W1 : W2);
  Wt[idx] = f2bf(W[(size_t)k * C_ + n]);
}

__global__ __launch_bounds__(256) void bias_cat(
    const float* __restrict__ bq, const float* __restrict__ bk,
    const float* __restrict__ bv, float* __restrict__ out) {
  int i = blockIdx.x * 256 + threadIdx.x;
  if (i < 3072)
    out[i] = (i < 1024) ? bq[i] : ((i < 2048) ? bk[i - 1024] : bv[i - 2048]);
}

// -------- GEMM 128x128 tile (QKV, N=3072); Q third scaled by K1C --------
__global__ __launch_bounds__(256) void gemm128(
    const ushort_t* __restrict__ A, const ushort_t* __restrict__ Bt,
    const float* __restrict__ bias, ushort_t* __restrict__ Cm,
    int M, int N, int K) {
  __shared__ ushort_t As[128 * 32];
  __shared__ ushort_t Bs[128 * 32];
  int t = threadIdx.x;
  int m0 = blockIdx.y * 128, n0 = blockIdx.x * 128;
  int w = t >> 6, l = t & 63;
  int wr = w >> 1, wc = w & 1;
  int lo = l & 15, hi = l >> 4;
  f32x4 acc[4][4] = {};
  int srow = t >> 2, scol = (t & 3) * 8;
  const ushort_t* Ag = A  + (size_t)(m0 + srow) * K + scol;
  const ushort_t* Bg = Bt + (size_t)(n0 + srow) * K + scol;
  ushort_t* AsP = As + t * 8;
  ushort_t* BsP = Bs + t * 8;
  for (int k0 = 0; k0 < K; k0 += 32) {
    gl_lds16(Ag + k0,          AsP);
    gl_lds16(Ag + 64 * K + k0, AsP + 64 * 32);
    gl_lds16(Bg + k0,          BsP);
    gl_lds16(Bg + 64 * K + k0, BsP + 64 * 32);
    __syncthreads();
    short8 af[4], bfr[4];
    #pragma unroll
    for (int i = 0; i < 4; i++)
      af[i] = *(const short8*)&As[(wr * 64 + i * 16 + lo) * 32 + hi * 8];
    #pragma unroll
    for (int j = 0; j < 4; j++)
      bfr[j] = *(const short8*)&Bs[(wc * 64 + j * 16 + lo) * 32 + hi * 8];
    #pragma unroll
    for (int i = 0; i < 4; i++)
      #pragma unroll
      for (int j = 0; j < 4; j++)
        acc[i][j] = mfma16(af[i], bfr[j], acc[i][j]);
    __syncthreads();
  }
  float qs = (n0 < C_) ? K1C : 1.0f;
  #pragma unroll
  for (int i = 0; i < 4; i++) {
    int m = m0 + wr * 64 + i * 16 + hi * 4;
    #pragma unroll
    for (int j = 0; j < 4; j++) {
      int n = n0 + wc * 64 + j * 16 + lo;
      float bv = bias[n];
      #pragma unroll
      for (int r = 0; r < 4; r++)
        Cm[(size_t)(m + r) * N + n] = f2bf((acc[i][j][r] + bv) * qs);
    }
  }
}

// ---------------- GEMM 128x64 tile (N=1024 GEMMs) ----------------
template<int OUT_BF16, int RELU, int HAS_RES>
__global__ __launch_bounds__(256) void gemm64(
    const ushort_t* __restrict__ A, const ushort_t* __restrict__ Bt,
    const float* __restrict__ bias, const float* __restrict__ res,
    void* __restrict__ Cm, int M, int N, int K) {
  __shared__ ushort_t As[128 * 32];
  __shared__ ushort_t Bs[64 * 32];
  int t = threadIdx.x;
  int m0 = blockIdx.y * 128, n0 = blockIdx.x * 64;
  int w = t >> 6, l = t & 63;
  int wr = w >> 1, wc = w & 1;
  int lo = l & 15, hi = l >> 4;
  f32x4 acc[4][2] = {};
  int srow = t >> 2, scol = (t & 3) * 8;
  const ushort_t* Ag = A  + (size_t)(m0 + srow) * K + scol;
  const ushort_t* Bg = Bt + (size_t)(n0 + srow) * K + scol;
  ushort_t* AsP = As + t * 8;
  ushort_t* BsP = Bs + t * 8;
  for (int k0 = 0; k0 < K; k0 += 32) {
    gl_lds16(Ag + k0,          AsP);
    gl_lds16(Ag + 64 * K + k0, AsP + 64 * 32);
    gl_lds16(Bg + k0,          BsP);
    __syncthreads();
    short8 af[4], bfr[2];
    #pragma unroll
    for (int i = 0; i < 4; i++)
      af[i] = *(const short8*)&As[(wr * 64 + i * 16 + lo) * 32 + hi * 8];
    #pragma unroll
    for (int j = 0; j < 2; j++)
      bfr[j] = *(const short8*)&Bs[(wc * 32 + j * 16 + lo) * 32 + hi * 8];
    #pragma unroll
    for (int i = 0; i < 4; i++)
      #pragma unroll
      for (int j = 0; j < 2; j++)
        acc[i][j] = mfma16(af[i], bfr[j], acc[i][j]);
    __syncthreads();
  }
  #pragma unroll
  for (int i = 0; i < 4; i++) {
    int m = m0 + wr * 64 + i * 16 + hi * 4;
    #pragma unroll
    for (int j = 0; j < 2; j++) {
      int n = n0 + wc * 32 + j * 16 + lo;
      float bv = bias[n];
      #pragma unroll
      for (int r = 0; r < 4; r++) {
        float v = acc[i][j][r] + bv;
        if (HAS_RES) v += res[(size_t)(m + r) * N + n];
        if (RELU) v = fmaxf(v, 0.f);
        if (OUT_BF16) ((ushort_t*)Cm)[(size_t)(m + r) * N + n] = f2bf(v);
        else          ((float*)Cm)[(size_t)(m + r) * N + n] = v;
      }
    }
  }
}

// ---- stats: partial col-sums. 1 wave = 16 k-rows, q-chunk of 1024 ----
// y<128: i=y, c=1 (q in [1024,2048)); y>=128: i=y-128 (<64), c=0.
__global__ __launch_bounds__(64) void attn_stats(
    const ushort_t* __restrict__ QKV, float* __restrict__ sp0,
    float* __restrict__ sp1) {
  int bh = blockIdx.x, b = bh >> 4, h = bh & 15;
  int y = blockIdx.y;
  int i = (y < 128) ? y : (y - 128);
  int c = (y < 128) ? 1 : 0;
  int k0 = i * 16;
  int qd = k0 >> 6;
  int qtb = (c * 16 > qd) ? c * 16 : qd;
  int qte = (c + 1) * 16;
  int l = threadIdx.x, lo = l & 15, hi = l >> 4;
  const ushort_t* Kb = QKV + (size_t)b * T_ * C3 + C_ + h * HS_;
  const ushort_t* Qb = QKV + (size_t)b * T_ * C3 + h * HS_;
  short8 ka[2];
  #pragma unroll
  for (int cc = 0; cc < 2; cc++)
    ka[cc] = *(const short8*)(Kb + (size_t)(k0 + lo) * C3 + cc * 32 + hi * 8);
  float s[4] = {};

  auto loadq = [&](short8 (&QB)[4][2], int qt) {
    #pragma unroll
    for (int qj = 0; qj < 4; qj++)
      #pragma unroll
      for (int cc = 0; cc < 2; cc++)
        QB[qj][cc] = *(const short8*)(Qb +
            (size_t)(qt * 64 + qj * 16 + lo) * C3 + cc * 32 + hi * 8);
  };
  auto compute = [&](short8 (&QB)[4][2], int qt) {
    bool diag = (qt == qd);
    #pragma unroll
    for (int qj = 0; qj < 4; qj++) {
      f32x4 sf = {};
      sf = mfma16(ka[0], QB[qj][0], sf);
      sf = mfma16(ka[1], QB[qj][1], sf);
      if (diag) {
        int q = qt * 64 + qj * 16 + lo;
        #pragma unroll
        for (int r = 0; r < 4; r++) {
          int k = k0 + hi * 4 + r;
          s[r] += (q >= k) ? exp2f(sf[r]) : 0.f;
        }
      } else {
        #pragma unroll
        for (int r = 0; r < 4; r++) s[r] += exp2f(sf[r]);
      }
    }
  };

  short8 qA[4][2], qB[4][2];
  loadq(qA, qtb);
  int qt = qtb;
  while (true) {
    if (qt + 1 < qte) loadq(qB, qt + 1);
    compute(qA, qt);
    if (++qt >= qte) break;
    if (qt + 1 < qte) loadq(qA, qt + 1);
    compute(qB, qt);
    if (++qt >= qte) break;
  }

  #pragma unroll
  for (int off = 1; off < 16; off <<= 1)
    #pragma unroll
    for (int r = 0; r < 4; r++)
      s[r] += __shfl_xor(s[r], off);
  if (lo == 0) {
    float* sp = c ? sp1 : sp0;
    #pragma unroll
    for (int r = 0; r < 4; r++)
      sp[(size_t)bh * T_ + k0 + hi * 4 + r] = s[r];
  }
}

// ---- V' = V * dinv (dinv = 1/(sp0+sp1)), per-head transpose to (bh,HS,T) ----
__global__ __launch_bounds__(256) void transpose_v(
    const ushort_t* __restrict__ QKV, const float* __restrict__ sp0,
    const float* __restrict__ sp1, ushort_t* __restrict__ Vt) {
  int t0 = blockIdx.x * 64;
  int bh = blockIdx.y; int b = bh >> 4, h = bh & 15;
  __shared__ ushort_t tile[64][65];
  __shared__ float di[64];
  int tid = threadIdx.x;
  if (tid < 64) {
    int kg = t0 + tid;
    float s = sp1[(size_t)bh * T_ + kg];
    if (kg < 1024) s += sp0[(size_t)bh * T_ + kg];
    di[tid] = 1.0f / s;
  }
  __syncthreads();
  #pragma unroll
  for (int i = 0; i < 16; i++) {
    int idx = i * 256 + tid;
    int tt = idx >> 6, dd = idx & 63;
    float v = bf2f(QKV[(size_t)(b * T_ + t0 + tt) * C3 + 2 * C_ + h * HS_ + dd]);
    tile[tt][dd] = f2bf(v * di[tt]);
  }
  __syncthreads();
  #pragma unroll
  for (int i = 0; i < 16; i++) {
    int idx = i * 256 + tid;
    int dd = idx >> 6, tt = idx & 63;
    Vt[((size_t)(bh * HS_ + dd)) * T_ + t0 + tt] = tile[tt][dd];
  }
}

// ---- pv: partial att sums. 1 wave = 16 q-rows, k-chunk of 1024 ----
// y<128: t=127-y, c=0; y>=128: t=255-y (in [64,128)), c=1.
__global__ __launch_bounds__(64) void attn_pv(
    const ushort_t* __restrict__ QKV, const ushort_t* __restrict__ Vt,
    float* __restrict__ p0, float* __restrict__ p1) {
  int bh = blockIdx.x, b = bh >> 4, h = bh & 15;
  int y = blockIdx.y;
  int t = (y < 128) ? (127 - y) : (255 - y);
  int c = (y < 128) ? 0 : 1;
  int q0 = t * 16;
  int nk = (t >> 1) + 1;                    // # of 32-wide k-tiles
  int ktb = c * 32;
  int kte = (nk < (c + 1) * 32) ? nk : (c + 1) * 32;
  int l = threadIdx.x, lo = l & 15, hi = l >> 4;
  __shared__ ushort_t Ps[16 * 32];
  char* PsB = (char*)Ps;
  const ushort_t* Qb = QKV + (size_t)b * T_ * C3 + h * HS_;
  const ushort_t* Kb = QKV + (size_t)b * T_ * C3 + C_ + h * HS_;
  const ushort_t* Vb = Vt + (size_t)bh * HS_ * T_;
  short8 qa[2];
  #pragma unroll
  for (int cc = 0; cc < 2; cc++)
    qa[cc] = *(const short8*)(Qb + (size_t)(q0 + lo) * C3 + cc * 32 + hi * 8);
  f32x4 oacc[4] = {};

  auto loadkv = [&](short8 (&KA)[2][2], short8 (&VB)[4], int kt) {
    #pragma unroll
    for (int kh = 0; kh < 2; kh++)
      #pragma unroll
      for (int cc = 0; cc < 2; cc++)
        KA[kh][cc] = *(const short8*)(Kb +
            (size_t)(kt * 32 + kh * 16 + lo) * C3 + cc * 32 + hi * 8);
    #pragma unroll
    for (int j = 0; j < 4; j++)
      VB[j] = *(const short8*)(Vb + (size_t)(j * 16 + lo) * T_ + kt * 32 + hi * 8);
  };
  auto compute = [&](short8 (&KA)[2][2], short8 (&VB)[4], int kt) {
    f32x4 sf0 = {}, sf1 = {};
    sf0 = mfma16(KA[0][0], qa[0], sf0);
    sf0 = mfma16(KA[0][1], qa[1], sf0);
    sf1 = mfma16(KA[1][0], qa[0], sf1);
    sf1 = mfma16(KA[1][1], qa[1], sf1);
    bool tail = (kt == nk - 1);
    int q = q0 + lo;
    #pragma unroll
    for (int kh = 0; kh < 2; kh++) {
      #pragma unroll
      for (int rp = 0; rp < 2; rp++) {
        float e0 = exp2f(kh ? sf1[2 * rp] : sf0[2 * rp]);
        float e1 = exp2f(kh ? sf1[2 * rp + 1] : sf0[2 * rp + 1]);
        int kk = kh * 16 + hi * 4 + 2 * rp;
        if (tail) {
          int k = kt * 32 + kk;
          e0 = (k     <= q) ? e0 : 0.f;
          e1 = (k + 1 <= q) ? e1 : 0.f;
        }
        unsigned u = pk2(e0, e1);
        *(unsigned*)(PsB + lo * 64 + ((kk & 7) * 2) +
                     (((kk >> 3) ^ (lo & 3)) << 4)) = u;
      }
    }
    // same-wave LDS RAW (in-order DS pipe), read P as A-frag rows q=lo
    short8 pa = *(const short8*)(PsB + lo * 64 + ((hi ^ (lo & 3)) << 4));
    #pragma unroll
    for (int j = 0; j < 4; j++)
      oacc[j] = mfma16(pa, VB[j], oacc[j]);
  };

  short8 kA[2][2], vA[4], kB[2][2], vB4[4];
  loadkv(kA, vA, ktb);
  int kt = ktb;
  while (true) {
    if (kt + 1 < kte) loadkv(kB, vB4, kt + 1);
    compute(kA, vA, kt);
    if (++kt >= kte) break;
    if (kt + 1 < kte) loadkv(kA, vA, kt + 1);
    compute(kB, vB4, kt);
    if (++kt >= kte) break;
  }

  float* dst = c ? (p1 + (((size_t)bh * 1024 + (q0 - 1024)) << 6))
                 : (p0 + (((size_t)bh * 2048 + q0) << 6));
  #pragma unroll
  for (int j = 0; j < 4; j++)
    #pragma unroll
    for (int r = 0; r < 4; r++)
      dst[(hi * 4 + r) * 64 + j * 16 + lo] = oacc[j][r];
}

// ---- att_reduce: att[q,d] = part0 + (q>=1024 ? part1 : 0), bf16 ----
__global__ __launch_bounds__(256) void att_reduce(
    const float* __restrict__ p0, const float* __restrict__ p1,
    ushort_t* __restrict__ att) {
  int idx = blockIdx.x * 256 + threadIdx.x;   // 32*2048*32 pairs
  int d2 = idx & 31;
  int q  = (idx >> 5) & 2047;
  int bh = idx >> 16;
  int d = d2 * 2;
  float2 a = *(const float2*)&p0[(((size_t)bh * 2048 + q) << 6) + d];
  float x0 = a.x, x1 = a.y;
  if (q >= 1024) {
    float2 bb = *(const float2*)&p1[(((size_t)bh * 1024 + (q - 1024)) << 6) + d];
    x0 += bb.x; x1 += bb.y;
  }
  int b = bh >> 4, h = bh & 15;
  *(unsigned*)&att[((size_t)(b * T_ + q) * C_) + h * HS_ + d] = pk2(x0, x1);
}

extern "C" void kernel_launch(void* const* d_in, const int* in_sizes, int n_in,
                              void* d_out, int out_size, void* d_ws, size_t ws_size,
                              hipStream_t stream) {
  const float* x   = (const float*)d_in[0];
  const float* Wq  = (const float*)d_in[1];
  const float* bq  = (const float*)d_in[2];
  const float* Wk  = (const float*)d_in[3];
  const float* bk  = (const float*)d_in[4];
  const float* Wv  = (const float*)d_in[5];
  const float* bv  = (const float*)d_in[6];
  const float* Wo  = (const float*)d_in[7];
  const float* bo  = (const float*)d_in[8];
  const float* g1  = (const float*)d_in[9];
  const float* b1  = (const float*)d_in[10];
  const float* g2  = (const float*)d_in[11];
  const float* b2  = (const float*)d_in[12];
  const float* W1  = (const float*)d_in[13];
  const float* bf1 = (const float*)d_in[14];
  const float* W2  = (const float*)d_in[15];
  const float* bf2 = (const float*)d_in[16];
  float* out = (float*)d_out;

  char* base = (char*)d_ws;
  const size_t MB = 1 << 20;
  ushort_t* QKVb  = (ushort_t*)(base);            // 24MB; first 8MB reused as att
  ushort_t* hb    = (ushort_t*)(base + 24 * MB);  // 8MB: LN1 out -> pv part1 -> h2b
  ushort_t* Vt    = (ushort_t*)(base + 32 * MB);  // 8MB: V' -> f1b
  float*    y     = (float*)   (base + 40 * MB);  // 16MB: pv part0 -> y
  ushort_t* Wqkvt = (ushort_t*)(base + 56 * MB);  // 6MB
  ushort_t* Wot   = (ushort_t*)(base + 62 * MB);  // 2MB
  ushort_t* W1t   = (ushort_t*)(base + 64 * MB);  // 2MB
  ushort_t* W2t   = (ushort_t*)(base + 66 * MB);  // 2MB
  float*    bqkv  = (float*)   (base + 68 * MB);  // 12KB
  float*    sp0   = (float*)   (base + 68 * MB + 65536);       // 256KB
  float*    sp1   = (float*)   (base + 68 * MB + 65536 + 262144); // 256KB
  float*    pvp0  = y;                            // 16MB (dead until gemm64-out)
  float*    pvp1  = (float*)hb;                   // 8MB  (LN1 out already consumed)

  conv_wqkv3<<<12288, 256, 0, stream>>>(Wq, Wk, Wv, Wqkvt);
  conv_wt3  <<<12288, 256, 0, stream>>>(Wo, W1, W2, Wot);
  bias_cat  <<<12, 256, 0, stream>>>(bq, bk, bv, bqkv);

  ln_bf16<<<NROWS, 256, 0, stream>>>(x, g1, b1, hb);

  gemm128<<<dim3(C3 / 128, NROWS / 128), 256, 0, stream>>>(
      hb, Wqkvt, bqkv, QKVb, NROWS, C3, C_);

  attn_stats<<<dim3(32, 192), 64, 0, stream>>>(QKVb, sp0, sp1);
  transpose_v<<<dim3(T_ / 64, 32), 256, 0, stream>>>(QKVb, sp0, sp1, Vt);
  attn_pv<<<dim3(32, 192), 64, 0, stream>>>(QKVb, Vt, pvp0, pvp1);

  ushort_t* attb = QKVb;   // Q region dead after pv
  att_reduce<<<8192, 256, 0, stream>>>(pvp0, pvp1, attb);

  dim3 g64(C_ / 64, NROWS / 128);
  gemm64<0,0,1><<<g64, 256, 0, stream>>>(attb, Wot, bo, x, y, NROWS, C_, C_);

  ushort_t* h2b = hb;
  ln_bf16<<<NROWS, 256, 0, stream>>>(y, g2, b2, h2b);
  ushort_t* f1b = Vt;
  gemm64<1,1,0><<<g64, 256, 0, stream>>>(h2b, W1t, bf1, nullptr, f1b, NROWS, C_, C_);
  gemm64<0,0,1><<<g64, 256, 0, stream>>>(f1b, W2t, bf2, y, out, NROWS, C_, C_);
}

// Round 6
// 270.950 us; speedup vs baseline: 1.3472x; 1.3472x over previous
//
#include <hip/hip_runtime.h>
#include <hip/hip_bf16.h>
#include <math.h>

// Transformer block B=2 T=2048 C=1024 H=16 HS=64.
// R6: attention on 32x32x16 MFMA with fully in-register P.
//  S^T = mfma(A=K, B=Q) -> D[col=lane&31=q][rows=k in 16 regs]. pk2 + shfl_xor(32)
//  converts P directly to the PV A-fragment (no LDS roundtrip, no bank conflicts).
//  Column-softmax (query-axis quirk): stats = per-k col sums (exp2-only, Q
//  pre-scaled by 0.125*log2e in QKV epilogue), dinv folded into V'.
//  32 rows/wave, 1-wave blocks, 2048 blocks big-first, K/V ping-pong prefetch.

#define B_   2
#define T_   2048
#define C_   1024
#define H_   16
#define HS_  64
#define NROWS 4096
#define C3   3072
#define K1C  0.1803368801111244f    // 0.125 * log2(e), folded into Q

typedef unsigned short ushort_t;
typedef __attribute__((ext_vector_type(8))) short short8;
typedef __attribute__((ext_vector_type(4))) float f32x4;
typedef __attribute__((ext_vector_type(16))) float f32x16;

__device__ __forceinline__ ushort_t f2bf(float f) {
  __hip_bfloat16 h = __float2bfloat16(f);
  ushort_t u; __builtin_memcpy(&u, &h, 2); return u;
}
__device__ __forceinline__ float bf2f(ushort_t u) {
  union { unsigned u; float f; } v; v.u = ((unsigned)u) << 16;
  return v.f;
}
__device__ __forceinline__ unsigned pk2(float a, float b) {
  __hip_bfloat162 t = __float22bfloat162_rn(make_float2(a, b));
  unsigned u; __builtin_memcpy(&u, &t, 4); return u;
}
__device__ __forceinline__ short8 mk8(unsigned a, unsigned b, unsigned c, unsigned d) {
  union { unsigned u[4]; short8 s; } t;
  t.u[0] = a; t.u[1] = b; t.u[2] = c; t.u[3] = d; return t.s;
}
__device__ __forceinline__ f32x4 mfma16(short8 a, short8 b, f32x4 c) {
  return __builtin_amdgcn_mfma_f32_16x16x32_bf16(a, b, c, 0, 0, 0);
}
__device__ __forceinline__ f32x16 mfma32(short8 a, short8 b, f32x16 c) {
  return __builtin_amdgcn_mfma_f32_32x32x16_bf16(a, b, c, 0, 0, 0);
}
typedef const __attribute__((address_space(1))) void g_void;
typedef __attribute__((address_space(3))) void l_void;
__device__ __forceinline__ void gl_lds16(const void* g, void* l) {
  __builtin_amdgcn_global_load_lds((g_void*)g, (l_void*)l, 16, 0, 0);
}

// ---------------- LayerNorm (f32 in -> bf16 out) ----------------
__global__ __launch_bounds__(256) void ln_bf16(
    const float* __restrict__ x, const float* __restrict__ g,
    const float* __restrict__ b, ushort_t* __restrict__ out) {
  int row = blockIdx.x;
  const float* xr = x + (size_t)row * C_;
  int t = threadIdx.x;
  float4 v = ((const float4*)xr)[t];
  float s  = v.x + v.y + v.z + v.w;
  float ss = v.x*v.x + v.y*v.y + v.z*v.z + v.w*v.w;
  #pragma unroll
  for (int off = 32; off > 0; off >>= 1) {
    s  += __shfl_down(s, off);
    ss += __shfl_down(ss, off);
  }
  __shared__ float red[2][4];
  int wid = t >> 6, lane = t & 63;
  if (lane == 0) { red[0][wid] = s; red[1][wid] = ss; }
  __syncthreads();
  if (t == 0) {
    float a = 0, c = 0;
    for (int i = 0; i < 4; i++) { a += red[0][i]; c += red[1][i]; }
    red[0][0] = a; red[1][0] = c;
  }
  __syncthreads();
  float mean = red[0][0] * (1.0f / C_);
  float var  = red[1][0] * (1.0f / C_) - mean * mean;
  float r = rsqrtf(var + 1e-5f);
  float4 gv = ((const float4*)g)[t];
  float4 bv = ((const float4*)b)[t];
  ushort4 o;
  o.x = f2bf((v.x - mean) * r * gv.x + bv.x);
  o.y = f2bf((v.y - mean) * r * gv.y + bv.y);
  o.z = f2bf((v.z - mean) * r * gv.z + bv.z);
  o.w = f2bf((v.w - mean) * r * gv.w + bv.w);
  ((ushort4*)(out + (size_t)row * C_))[t] = o;
}

// ---- Wq,Wk,Wv (H,C,HS) f32 -> concatenated (3072, 1024) bf16 N-major ----
__global__ __launch_bounds__(256) void conv_wqkv3(
    const float* __restrict__ Wq, const float* __restrict__ Wk,
    const float* __restrict__ Wv, ushort_t* __restrict__ Wt) {
  int idx = blockIdx.x * 256 + threadIdx.x;
  int n = idx >> 10, c = idx & 1023;
  int sel = n >> 10, nn = n & 1023;
  const float* W = (sel == 0) ? Wq : ((sel == 1) ? Wk : Wv);
  Wt[idx] = f2bf(W[((size_t)(nn >> 6) * C_ + c) * HS_ + (nn & 63)]);
}

// ---- Wo,W1,W2 (K,N) f32 -> three contiguous (N,K) bf16 blocks ----
__global__ __launch_bounds__(256) void conv_wt3(
    const float* __restrict__ W0, const float* __restrict__ W1,
    const float* __restrict__ W2, ushort_t* __restrict__ Wt) {
  int idx = blockIdx.x * 256 + threadIdx.x;
  int sel = idx >> 20, rem = idx & 1048575;
  int n = rem >> 10, k = rem & 1023;
  const float* W = (sel == 0) ? W0 : ((sel == 1) ? W1 : W2);
  Wt[idx] = f2bf(W[(size_t)k * C_ + n]);
}

__global__ __launch_bounds__(256) void bias_cat(
    const float* __restrict__ bq, const float* __restrict__ bk,
    const float* __restrict__ bv, float* __restrict__ out) {
  int i = blockIdx.x * 256 + threadIdx.x;
  if (i < 3072)
    out[i] = (i < 1024) ? bq[i] : ((i < 2048) ? bk[i - 1024] : bv[i - 2048]);
}

// -------- GEMM 128x128 tile (QKV, N=3072); Q third scaled by K1C --------
__global__ __launch_bounds__(256) void gemm128(
    const ushort_t* __restrict__ A, const ushort_t* __restrict__ Bt,
    const float* __restrict__ bias, ushort_t* __restrict__ Cm,
    int M, int N, int K) {
  __shared__ ushort_t As[128 * 32];
  __shared__ ushort_t Bs[128 * 32];
  int t = threadIdx.x;
  int m0 = blockIdx.y * 128, n0 = blockIdx.x * 128;
  int w = t >> 6, l = t & 63;
  int wr = w >> 1, wc = w & 1;
  int lo = l & 15, hi = l >> 4;
  f32x4 acc[4][4] = {};
  int srow = t >> 2, scol = (t & 3) * 8;
  const ushort_t* Ag = A  + (size_t)(m0 + srow) * K + scol;
  const ushort_t* Bg = Bt + (size_t)(n0 + srow) * K + scol;
  ushort_t* AsP = As + t * 8;
  ushort_t* BsP = Bs + t * 8;
  for (int k0 = 0; k0 < K; k0 += 32) {
    gl_lds16(Ag + k0,          AsP);
    gl_lds16(Ag + 64 * K + k0, AsP + 64 * 32);
    gl_lds16(Bg + k0,          BsP);
    gl_lds16(Bg + 64 * K + k0, BsP + 64 * 32);
    __syncthreads();
    short8 af[4], bfr[4];
    #pragma unroll
    for (int i = 0; i < 4; i++)
      af[i] = *(const short8*)&As[(wr * 64 + i * 16 + lo) * 32 + hi * 8];
    #pragma unroll
    for (int j = 0; j < 4; j++)
      bfr[j] = *(const short8*)&Bs[(wc * 64 + j * 16 + lo) * 32 + hi * 8];
    #pragma unroll
    for (int i = 0; i < 4; i++)
      #pragma unroll
      for (int j = 0; j < 4; j++)
        acc[i][j] = mfma16(af[i], bfr[j], acc[i][j]);
    __syncthreads();
  }
  float qs = (n0 < C_) ? K1C : 1.0f;
  #pragma unroll
  for (int i = 0; i < 4; i++) {
    int m = m0 + wr * 64 + i * 16 + hi * 4;
    #pragma unroll
    for (int j = 0; j < 4; j++) {
      int n = n0 + wc * 64 + j * 16 + lo;
      float bv = bias[n];
      #pragma unroll
      for (int r = 0; r < 4; r++)
        Cm[(size_t)(m + r) * N + n] = f2bf((acc[i][j][r] + bv) * qs);
    }
  }
}

// ---------------- GEMM 128x64 tile (N=1024 GEMMs) ----------------
template<int OUT_BF16, int RELU, int HAS_RES>
__global__ __launch_bounds__(256) void gemm64(
    const ushort_t* __restrict__ A, const ushort_t* __restrict__ Bt,
    const float* __restrict__ bias, const float* __restrict__ res,
    void* __restrict__ Cm, int M, int N, int K) {
  __shared__ ushort_t As[128 * 32];
  __shared__ ushort_t Bs[64 * 32];
  int t = threadIdx.x;
  int m0 = blockIdx.y * 128, n0 = blockIdx.x * 64;
  int w = t >> 6, l = t & 63;
  int wr = w >> 1, wc = w & 1;
  int lo = l & 15, hi = l >> 4;
  f32x4 acc[4][2] = {};
  int srow = t >> 2, scol = (t & 3) * 8;
  const ushort_t* Ag = A  + (size_t)(m0 + srow) * K + scol;
  const ushort_t* Bg = Bt + (size_t)(n0 + srow) * K + scol;
  ushort_t* AsP = As + t * 8;
  ushort_t* BsP = Bs + t * 8;
  for (int k0 = 0; k0 < K; k0 += 32) {
    gl_lds16(Ag + k0,          AsP);
    gl_lds16(Ag + 64 * K + k0, AsP + 64 * 32);
    gl_lds16(Bg + k0,          BsP);
    __syncthreads();
    short8 af[4], bfr[2];
    #pragma unroll
    for (int i = 0; i < 4; i++)
      af[i] = *(const short8*)&As[(wr * 64 + i * 16 + lo) * 32 + hi * 8];
    #pragma unroll
    for (int j = 0; j < 2; j++)
      bfr[j] = *(const short8*)&Bs[(wc * 32 + j * 16 + lo) * 32 + hi * 8];
    #pragma unroll
    for (int i = 0; i < 4; i++)
      #pragma unroll
      for (int j = 0; j < 2; j++)
        acc[i][j] = mfma16(af[i], bfr[j], acc[i][j]);
    __syncthreads();
  }
  #pragma unroll
  for (int i = 0; i < 4; i++) {
    int m = m0 + wr * 64 + i * 16 + hi * 4;
    #pragma unroll
    for (int j = 0; j < 2; j++) {
      int n = n0 + wc * 32 + j * 16 + lo;
      float bv = bias[n];
      #pragma unroll
      for (int r = 0; r < 4; r++) {
        float v = acc[i][j][r] + bv;
        if (HAS_RES) v += res[(size_t)(m + r) * N + n];
        if (RELU) v = fmaxf(v, 0.f);
        if (OUT_BF16) ((ushort_t*)Cm)[(size_t)(m + r) * N + n] = f2bf(v);
        else          ((float*)Cm)[(size_t)(m + r) * N + n] = v;
      }
    }
  }
}

// ---- stats: dinv[k] = 1/sum_{q>=k} exp2(s'). 1 wave, 32 k-rows (32x32 MFMA) ----
__global__ __launch_bounds__(64) void attn_stats(
    const ushort_t* __restrict__ QKV, float* __restrict__ dinv) {
  int bh = blockIdx.x, b = bh >> 4, h = bh & 15;
  int k0 = blockIdx.y * 32;
  int l = threadIdx.x, l31 = l & 31, hi32 = l >> 5;
  const ushort_t* Qb = QKV + (size_t)b * T_ * C3 + h * HS_;
  const ushort_t* Kb = Qb + C_;
  // A = K rows: lane row = k0+l31, d = c*16 + hi32*8
  short8 ka[4];
  #pragma unroll
  for (int c = 0; c < 4; c++)
    ka[c] = *(const short8*)(Kb + (size_t)(k0 + l31) * C3 + c * 16 + hi32 * 8);
  float s[16];
  #pragma unroll
  for (int r = 0; r < 16; r++) s[r] = 0.f;

  auto loadq = [&](short8 (&qf)[4], int qs) {
    #pragma unroll
    for (int c = 0; c < 4; c++)
      qf[c] = *(const short8*)(Qb + (size_t)(qs + l31) * C3 + c * 16 + hi32 * 8);
  };
  auto compute = [&](short8 (&qf)[4], int qs) {
    f32x16 d = {};
    #pragma unroll
    for (int c = 0; c < 4; c++) d = mfma32(ka[c], qf[c], d);
    if (qs == k0) {             // diagonal tile: mask q >= k
      int q = qs + l31;
      #pragma unroll
      for (int r = 0; r < 16; r++) {
        int k = k0 + (r & 3) + 8 * (r >> 2) + 4 * hi32;
        s[r] += (q >= k) ? exp2f(d[r]) : 0.f;
      }
    } else {
      #pragma unroll
      for (int r = 0; r < 16; r++) s[r] += exp2f(d[r]);
    }
  };

  short8 qA[4], qB[4];
  loadq(qA, k0);
  int qs = k0;
  while (true) {
    if (qs + 32 < T_) loadq(qB, qs + 32);
    compute(qA, qs);
    qs += 32; if (qs >= T_) break;
    if (qs + 32 < T_) loadq(qA, qs + 32);
    compute(qB, qs);
    qs += 32; if (qs >= T_) break;
  }
  // sum over q: butterfly within each 32-lane half
  #pragma unroll
  for (int off = 1; off < 32; off <<= 1)
    #pragma unroll
    for (int r = 0; r < 16; r++)
      s[r] += __shfl_xor(s[r], off);
  if (l31 == 0) {
    #pragma unroll
    for (int r = 0; r < 16; r++) {
      int k = k0 + (r & 3) + 8 * (r >> 2) + 4 * hi32;
      dinv[(size_t)bh * T_ + k] = 1.0f / s[r];
    }
  }
}

// ---- V' = V * dinv, per-head transpose to (bh, HS, T) ----
__global__ __launch_bounds__(256) void transpose_v(
    const ushort_t* __restrict__ QKV, const float* __restrict__ dinv,
    ushort_t* __restrict__ Vt) {
  int t0 = blockIdx.x * 64;
  int bh = blockIdx.y; int b = bh >> 4, h = bh & 15;
  __shared__ ushort_t tile[64][65];
  int tid = threadIdx.x;
  #pragma unroll
  for (int i = 0; i < 16; i++) {
    int idx = i * 256 + tid;
    int tt = idx >> 6, dd = idx & 63;
    float v = bf2f(QKV[(size_t)(b * T_ + t0 + tt) * C3 + 2 * C_ + h * HS_ + dd]);
    tile[tt][dd] = f2bf(v * dinv[(size_t)bh * T_ + t0 + tt]);
  }
  __syncthreads();
  #pragma unroll
  for (int i = 0; i < 16; i++) {
    int idx = i * 256 + tid;
    int dd = idx >> 6, tt = idx & 63;
    Vt[((size_t)(bh * HS_ + dd)) * T_ + t0 + tt] = tile[tt][dd];
  }
}

// ---- PV: att[q,d] = sum_{k<=q} exp2(s') * V'[k,d]. 1 wave, 32 q-rows ----
// 32x32x16 MFMA; P stays in registers (pk2 + shfl_xor(32) -> PV A-frags).
__global__ __launch_bounds__(64) void attn_pv(
    const ushort_t* __restrict__ QKV, const ushort_t* __restrict__ Vt,
    ushort_t* __restrict__ att) {
  int bh = blockIdx.x, tile = 63 - blockIdx.y;   // big first
  int b = bh >> 4, h = bh & 15;
  int l = threadIdx.x, l31 = l & 31, hi32 = l >> 5;
  int q0 = tile * 32;
  const ushort_t* Qb = QKV + (size_t)b * T_ * C3 + h * HS_;
  const ushort_t* Kb = Qb + C_;
  const ushort_t* Vb = Vt + (size_t)bh * HS_ * T_;
  // Q as B-frags: lane col = q0+l31, d = c*16 + hi32*8
  short8 qf[4];
  #pragma unroll
  for (int c = 0; c < 4; c++)
    qf[c] = *(const short8*)(Qb + (size_t)(q0 + l31) * C3 + c * 16 + hi32 * 8);
  f32x16 o0 = {}, o1 = {};
  int nkt = tile + 1;

  auto loadK = [&](short8 (&ka)[4], int kt) {
    #pragma unroll
    for (int c = 0; c < 4; c++)
      ka[c] = *(const short8*)(Kb + (size_t)(kt * 32 + l31) * C3 + c * 16 + hi32 * 8);
  };
  auto loadV = [&](short8 (&vf)[4], int kt) {
    #pragma unroll
    for (int c16 = 0; c16 < 2; c16++)
      #pragma unroll
      for (int dh = 0; dh < 2; dh++)
        vf[c16 * 2 + dh] = *(const short8*)(Vb +
            (size_t)(dh * 32 + l31) * T_ + kt * 32 + c16 * 16 + hi32 * 8);
  };
  auto compute = [&](short8 (&ka)[4], short8 (&vf)[4], int kt) {
    f32x16 sacc = {};
    #pragma unroll
    for (int c = 0; c < 4; c++) sacc = mfma32(ka[c], qf[c], sacc);
    float e[16];
    if (kt == nkt - 1) {        // diagonal tile: mask k <= q
      int q = q0 + l31;
      #pragma unroll
      for (int r = 0; r < 16; r++) {
        int k = kt * 32 + (r & 3) + 8 * (r >> 2) + 4 * hi32;
        e[r] = (k <= q) ? exp2f(sacc[r]) : 0.f;
      }
    } else {
      #pragma unroll
      for (int r = 0; r < 16; r++) e[r] = exp2f(sacc[r]);
    }
    unsigned u[8], x[8];
    #pragma unroll
    for (int j = 0; j < 8; j++) u[j] = pk2(e[2 * j], e[2 * j + 1]);
    #pragma unroll
    for (int j = 0; j < 8; j++) x[j] = __shfl_xor(u[j], 32);
    // PV A-frags: k-chunk0 = rows 0..15, chunk1 = rows 16..31
    short8 pa0 = hi32 ? mk8(x[2], x[3], u[2], u[3]) : mk8(u[0], u[1], x[0], x[1]);
    short8 pa1 = hi32 ? mk8(x[6], x[7], u[6], u[7]) : mk8(u[4], u[5], x[4], x[5]);
    o0 = mfma32(pa0, vf[0], o0);   // k 0..15, d 0..31
    o1 = mfma32(pa0, vf[1], o1);   // k 0..15, d 32..63
    o0 = mfma32(pa1, vf[2], o0);   // k 16..31, d 0..31
    o1 = mfma32(pa1, vf[3], o1);
  };

  short8 kA[4], vA[4], kB[4], vB[4];
  loadK(kA, 0); loadV(vA, 0);
  int kt = 0;
  while (true) {
    if (kt + 1 < nkt) { loadK(kB, kt + 1); loadV(vB, kt + 1); }
    compute(kA, vA, kt);
    if (++kt >= nkt) break;
    if (kt + 1 < nkt) { loadK(kA, kt + 1); loadV(vA, kt + 1); }
    compute(kB, vB, kt);
    if (++kt >= nkt) break;
  }

  #pragma unroll
  for (int r = 0; r < 16; r++) {
    int q = q0 + (r & 3) + 8 * (r >> 2) + 4 * hi32;
    size_t base = (size_t)(b * T_ + q) * C_ + h * HS_;
    att[base + l31]      = f2bf(o0[r]);
    att[base + 32 + l31] = f2bf(o1[r]);
  }
}

extern "C" void kernel_launch(void* const* d_in, const int* in_sizes, int n_in,
                              void* d_out, int out_size, void* d_ws, size_t ws_size,
                              hipStream_t stream) {
  const float* x   = (const float*)d_in[0];
  const float* Wq  = (const float*)d_in[1];
  const float* bq  = (const float*)d_in[2];
  const float* Wk  = (const float*)d_in[3];
  const float* bk  = (const float*)d_in[4];
  const float* Wv  = (const float*)d_in[5];
  const float* bv  = (const float*)d_in[6];
  const float* Wo  = (const float*)d_in[7];
  const float* bo  = (const float*)d_in[8];
  const float* g1  = (const float*)d_in[9];
  const float* b1  = (const float*)d_in[10];
  const float* g2  = (const float*)d_in[11];
  const float* b2  = (const float*)d_in[12];
  const float* W1  = (const float*)d_in[13];
  const float* bf1 = (const float*)d_in[14];
  const float* W2  = (const float*)d_in[15];
  const float* bf2 = (const float*)d_in[16];
  float* out = (float*)d_out;

  char* base = (char*)d_ws;
  const size_t MB = 1 << 20;
  ushort_t* QKVb  = (ushort_t*)(base);            // 24MB
  ushort_t* hb    = (ushort_t*)(base + 24 * MB);  // 8MB: LN1 out -> att
  ushort_t* Vt    = (ushort_t*)(base + 32 * MB);  // 8MB: V' -> f1b
  float*    y     = (float*)   (base + 40 * MB);  // 16MB
  ushort_t* Wqkvt = (ushort_t*)(base + 56 * MB);  // 6MB
  ushort_t* Wot   = (ushort_t*)(base + 62 * MB);  // 2MB
  ushort_t* W1t   = (ushort_t*)(base + 64 * MB);  // 2MB
  ushort_t* W2t   = (ushort_t*)(base + 66 * MB);  // 2MB
  float*    bqkv  = (float*)   (base + 68 * MB);  // 12KB
  float*    dinv  = (float*)   (base + 68 * MB + 65536); // 256KB

  conv_wqkv3<<<12288, 256, 0, stream>>>(Wq, Wk, Wv, Wqkvt);
  conv_wt3  <<<12288, 256, 0, stream>>>(Wo, W1, W2, Wot);
  bias_cat  <<<12, 256, 0, stream>>>(bq, bk, bv, bqkv);

  ln_bf16<<<NROWS, 256, 0, stream>>>(x, g1, b1, hb);

  gemm128<<<dim3(C3 / 128, NROWS / 128), 256, 0, stream>>>(
      hb, Wqkvt, bqkv, QKVb, NROWS, C3, C_);

  attn_stats<<<dim3(32, 64), 64, 0, stream>>>(QKVb, dinv);
  transpose_v<<<dim3(T_ / 64, 32), 256, 0, stream>>>(QKVb, dinv, Vt);
  ushort_t* attb = hb;
  attn_pv<<<dim3(32, 64), 64, 0, stream>>>(QKVb, Vt, attb);

  dim3 g64(C_ / 64, NROWS / 128);
  gemm64<0,0,1><<<g64, 256, 0, stream>>>(attb, Wot, bo, x, y, NROWS, C_, C_);

  ushort_t* h2b = QKVb;
  ln_bf16<<<NROWS, 256, 0, stream>>>(y, g2, b2, h2b);
  ushort_t* f1b = Vt;
  gemm64<1,1,0><<<g64, 256, 0, stream>>>(h2b, W1t, bf1, nullptr, f1b, NROWS, C_, C_);
  gemm64<0,0,1><<<g64, 256, 0, stream>>>(f1b, W2t, bf2, y, out, NROWS, C_, C_);
}

// Round 7
// 262.193 us; speedup vs baseline: 1.3922x; 1.0334x over previous
//
#include <hip/hip_runtime.h>
#include <hip/hip_bf16.h>
#include <math.h>

// Transformer block B=2 T=2048 C=1024 H=16 HS=64.
// R7: attention = 4-wave workgroups, k-split (pv) / q-split (stats) within
// block, LDS tree-reduce. In-register P via pk2 + v_permlane32_swap_b32
// (VALU, replaces DS-pipe shfl). Column-softmax (query-axis quirk), exp2-only
// path (Q pre-scaled by 0.125*log2e in QKV epilogue), dinv folded into V'.

#define B_   2
#define T_   2048
#define C_   1024
#define H_   16
#define HS_  64
#define NROWS 4096
#define C3   3072
#define K1C  0.1803368801111244f    // 0.125 * log2(e), folded into Q

typedef unsigned short ushort_t;
typedef __attribute__((ext_vector_type(8))) short short8;
typedef __attribute__((ext_vector_type(4))) float f32x4;
typedef __attribute__((ext_vector_type(16))) float f32x16;

__device__ __forceinline__ ushort_t f2bf(float f) {
  __hip_bfloat16 h = __float2bfloat16(f);
  ushort_t u; __builtin_memcpy(&u, &h, 2); return u;
}
__device__ __forceinline__ float bf2f(ushort_t u) {
  union { unsigned u; float f; } v; v.u = ((unsigned)u) << 16;
  return v.f;
}
__device__ __forceinline__ unsigned pk2(float a, float b) {
  __hip_bfloat162 t = __float22bfloat162_rn(make_float2(a, b));
  unsigned u; __builtin_memcpy(&u, &t, 4); return u;
}
__device__ __forceinline__ short8 mk8(unsigned a, unsigned b, unsigned c, unsigned d) {
  union { unsigned u[4]; short8 s; } t;
  t.u[0] = a; t.u[1] = b; t.u[2] = c; t.u[3] = d; return t.s;
}
// v_permlane32_swap_b32: a.lanes[32:63] <-> b.lanes[0:31]
__device__ __forceinline__ void pl32swap(unsigned &a, unsigned &b) {
  asm("v_permlane32_swap_b32 %0, %1" : "+v"(a), "+v"(b));
}
__device__ __forceinline__ f32x4 mfma16(short8 a, short8 b, f32x4 c) {
  return __builtin_amdgcn_mfma_f32_16x16x32_bf16(a, b, c, 0, 0, 0);
}
__device__ __forceinline__ f32x16 mfma32(short8 a, short8 b, f32x16 c) {
  return __builtin_amdgcn_mfma_f32_32x32x16_bf16(a, b, c, 0, 0, 0);
}
typedef const __attribute__((address_space(1))) void g_void;
typedef __attribute__((address_space(3))) void l_void;
__device__ __forceinline__ void gl_lds16(const void* g, void* l) {
  __builtin_amdgcn_global_load_lds((g_void*)g, (l_void*)l, 16, 0, 0);
}

// ---------------- LayerNorm (f32 in -> bf16 out) ----------------
__global__ __launch_bounds__(256) void ln_bf16(
    const float* __restrict__ x, const float* __restrict__ g,
    const float* __restrict__ b, ushort_t* __restrict__ out) {
  int row = blockIdx.x;
  const float* xr = x + (size_t)row * C_;
  int t = threadIdx.x;
  float4 v = ((const float4*)xr)[t];
  float s  = v.x + v.y + v.z + v.w;
  float ss = v.x*v.x + v.y*v.y + v.z*v.z + v.w*v.w;
  #pragma unroll
  for (int off = 32; off > 0; off >>= 1) {
    s  += __shfl_down(s, off);
    ss += __shfl_down(ss, off);
  }
  __shared__ float red[2][4];
  int wid = t >> 6, lane = t & 63;
  if (lane == 0) { red[0][wid] = s; red[1][wid] = ss; }
  __syncthreads();
  if (t == 0) {
    float a = 0, c = 0;
    for (int i = 0; i < 4; i++) { a += red[0][i]; c += red[1][i]; }
    red[0][0] = a; red[1][0] = c;
  }
  __syncthreads();
  float mean = red[0][0] * (1.0f / C_);
  float var  = red[1][0] * (1.0f / C_) - mean * mean;
  float r = rsqrtf(var + 1e-5f);
  float4 gv = ((const float4*)g)[t];
  float4 bv = ((const float4*)b)[t];
  ushort4 o;
  o.x = f2bf((v.x - mean) * r * gv.x + bv.x);
  o.y = f2bf((v.y - mean) * r * gv.y + bv.y);
  o.z = f2bf((v.z - mean) * r * gv.z + bv.z);
  o.w = f2bf((v.w - mean) * r * gv.w + bv.w);
  ((ushort4*)(out + (size_t)row * C_))[t] = o;
}

// ---- Wq,Wk,Wv (H,C,HS) f32 -> concatenated (3072, 1024) bf16 N-major ----
__global__ __launch_bounds__(256) void conv_wqkv3(
    const float* __restrict__ Wq, const float* __restrict__ Wk,
    const float* __restrict__ Wv, ushort_t* __restrict__ Wt) {
  int idx = blockIdx.x * 256 + threadIdx.x;
  int n = idx >> 10, c = idx & 1023;
  int sel = n >> 10, nn = n & 1023;
  const float* W = (sel == 0) ? Wq : ((sel == 1) ? Wk : Wv);
  Wt[idx] = f2bf(W[((size_t)(nn >> 6) * C_ + c) * HS_ + (nn & 63)]);
}

// ---- Wo,W1,W2 (K,N) f32 -> three contiguous (N,K) bf16 blocks ----
__global__ __launch_bounds__(256) void conv_wt3(
    const float* __restrict__ W0, const float* __restrict__ W1,
    const float* __restrict__ W2, ushort_t* __restrict__ Wt) {
  int idx = blockIdx.x * 256 + threadIdx.x;
  int sel = idx >> 20, rem = idx & 1048575;
  int n = rem >> 10, k = rem & 1023;
  const float* W = (sel == 0) ? W0 : ((sel == 1) ? W1 : W2);
  Wt[idx] = f2bf(W[(size_t)k * C_ + n]);
}

__global__ __launch_bounds__(256) void bias_cat(
    const float* __restrict__ bq, const float* __restrict__ bk,
    const float* __restrict__ bv, float* __restrict__ out) {
  int i = blockIdx.x * 256 + threadIdx.x;
  if (i < 3072)
    out[i] = (i < 1024) ? bq[i] : ((i < 2048) ? bk[i - 1024] : bv[i - 2048]);
}

// -------- GEMM 128x128 tile (QKV, N=3072); Q third scaled by K1C --------
__global__ __launch_bounds__(256) void gemm128(
    const ushort_t* __restrict__ A, const ushort_t* __restrict__ Bt,
    const float* __restrict__ bias, ushort_t* __restrict__ Cm,
    int M, int N, int K) {
  __shared__ ushort_t As[128 * 32];
  __shared__ ushort_t Bs[128 * 32];
  int t = threadIdx.x;
  int m0 = blockIdx.y * 128, n0 = blockIdx.x * 128;
  int w = t >> 6, l = t & 63;
  int wr = w >> 1, wc = w & 1;
  int lo = l & 15, hi = l >> 4;
  f32x4 acc[4][4] = {};
  int srow = t >> 2, scol = (t & 3) * 8;
  const ushort_t* Ag = A  + (size_t)(m0 + srow) * K + scol;
  const ushort_t* Bg = Bt + (size_t)(n0 + srow) * K + scol;
  ushort_t* AsP = As + t * 8;
  ushort_t* BsP = Bs + t * 8;
  for (int k0 = 0; k0 < K; k0 += 32) {
    gl_lds16(Ag + k0,          AsP);
    gl_lds16(Ag + 64 * K + k0, AsP + 64 * 32);
    gl_lds16(Bg + k0,          BsP);
    gl_lds16(Bg + 64 * K + k0, BsP + 64 * 32);
    __syncthreads();
    short8 af[4], bfr[4];
    #pragma unroll
    for (int i = 0; i < 4; i++)
      af[i] = *(const short8*)&As[(wr * 64 + i * 16 + lo) * 32 + hi * 8];
    #pragma unroll
    for (int j = 0; j < 4; j++)
      bfr[j] = *(const short8*)&Bs[(wc * 64 + j * 16 + lo) * 32 + hi * 8];
    #pragma unroll
    for (int i = 0; i < 4; i++)
      #pragma unroll
      for (int j = 0; j < 4; j++)
        acc[i][j] = mfma16(af[i], bfr[j], acc[i][j]);
    __syncthreads();
  }
  float qs = (n0 < C_) ? K1C : 1.0f;
  #pragma unroll
  for (int i = 0; i < 4; i++) {
    int m = m0 + wr * 64 + i * 16 + hi * 4;
    #pragma unroll
    for (int j = 0; j < 4; j++) {
      int n = n0 + wc * 64 + j * 16 + lo;
      float bv = bias[n];
      #pragma unroll
      for (int r = 0; r < 4; r++)
        Cm[(size_t)(m + r) * N + n] = f2bf((acc[i][j][r] + bv) * qs);
    }
  }
}

// ---------------- GEMM 128x64 tile (N=1024 GEMMs) ----------------
template<int OUT_BF16, int RELU, int HAS_RES>
__global__ __launch_bounds__(256) void gemm64(
    const ushort_t* __restrict__ A, const ushort_t* __restrict__ Bt,
    const float* __restrict__ bias, const float* __restrict__ res,
    void* __restrict__ Cm, int M, int N, int K) {
  __shared__ ushort_t As[128 * 32];
  __shared__ ushort_t Bs[64 * 32];
  int t = threadIdx.x;
  int m0 = blockIdx.y * 128, n0 = blockIdx.x * 64;
  int w = t >> 6, l = t & 63;
  int wr = w >> 1, wc = w & 1;
  int lo = l & 15, hi = l >> 4;
  f32x4 acc[4][2] = {};
  int srow = t >> 2, scol = (t & 3) * 8;
  const ushort_t* Ag = A  + (size_t)(m0 + srow) * K + scol;
  const ushort_t* Bg = Bt + (size_t)(n0 + srow) * K + scol;
  ushort_t* AsP = As + t * 8;
  ushort_t* BsP = Bs + t * 8;
  for (int k0 = 0; k0 < K; k0 += 32) {
    gl_lds16(Ag + k0,          AsP);
    gl_lds16(Ag + 64 * K + k0, AsP + 64 * 32);
    gl_lds16(Bg + k0,          BsP);
    __syncthreads();
    short8 af[4], bfr[2];
    #pragma unroll
    for (int i = 0; i < 4; i++)
      af[i] = *(const short8*)&As[(wr * 64 + i * 16 + lo) * 32 + hi * 8];
    #pragma unroll
    for (int j = 0; j < 2; j++)
      bfr[j] = *(const short8*)&Bs[(wc * 32 + j * 16 + lo) * 32 + hi * 8];
    #pragma unroll
    for (int i = 0; i < 4; i++)
      #pragma unroll
      for (int j = 0; j < 2; j++)
        acc[i][j] = mfma16(af[i], bfr[j], acc[i][j]);
    __syncthreads();
  }
  #pragma unroll
  for (int i = 0; i < 4; i++) {
    int m = m0 + wr * 64 + i * 16 + hi * 4;
    #pragma unroll
    for (int j = 0; j < 2; j++) {
      int n = n0 + wc * 32 + j * 16 + lo;
      float bv = bias[n];
      #pragma unroll
      for (int r = 0; r < 4; r++) {
        float v = acc[i][j][r] + bv;
        if (HAS_RES) v += res[(size_t)(m + r) * N + n];
        if (RELU) v = fmaxf(v, 0.f);
        if (OUT_BF16) ((ushort_t*)Cm)[(size_t)(m + r) * N + n] = f2bf(v);
        else          ((float*)Cm)[(size_t)(m + r) * N + n] = v;
      }
    }
  }
}

// ---- stats: dinv[k] = 1/sum_{q>=k} exp2(s'). 4 waves split q, LDS reduce ----
__global__ __launch_bounds__(256) void attn_stats(
    const ushort_t* __restrict__ QKV, float* __restrict__ dinv) {
  int bh = blockIdx.x, b = bh >> 4, h = bh & 15;
  int k0 = blockIdx.y * 32;
  int t = threadIdx.x, w = t >> 6, l = t & 63, l31 = l & 31, hi32 = l >> 5;
  __shared__ float red[2][16][64];   // 8KB
  const ushort_t* Qb = QKV + (size_t)b * T_ * C3 + h * HS_;
  const ushort_t* Kb = Qb + C_;
  short8 ka[4];
  #pragma unroll
  for (int c = 0; c < 4; c++)
    ka[c] = *(const short8*)(Kb + (size_t)(k0 + l31) * C3 + c * 16 + hi32 * 8);
  float s[16];
  #pragma unroll
  for (int r = 0; r < 16; r++) s[r] = 0.f;

  for (int qs = k0 + w * 32; qs < T_; qs += 128) {
    short8 qf[4];
    #pragma unroll
    for (int c = 0; c < 4; c++)
      qf[c] = *(const short8*)(Qb + (size_t)(qs + l31) * C3 + c * 16 + hi32 * 8);
    f32x16 d = {};
    #pragma unroll
    for (int c = 0; c < 4; c++) d = mfma32(ka[c], qf[c], d);
    if (qs == k0) {              // diagonal tile (wave 0 only): mask q >= k
      int q = qs + l31;
      #pragma unroll
      for (int r = 0; r < 16; r++) {
        int k = k0 + (r & 3) + 8 * (r >> 2) + 4 * hi32;
        s[r] += (q >= k) ? exp2f(d[r]) : 0.f;
      }
    } else {
      #pragma unroll
      for (int r = 0; r < 16; r++) s[r] += exp2f(d[r]);
    }
  }
  // cross-wave tree reduce
  if (w >= 2) {
    #pragma unroll
    for (int r = 0; r < 16; r++) red[w - 2][r][l] = s[r];
  }
  __syncthreads();
  if (w < 2) {
    #pragma unroll
    for (int r = 0; r < 16; r++) s[r] += red[w][r][l];
  }
  __syncthreads();
  if (w == 1) {
    #pragma unroll
    for (int r = 0; r < 16; r++) red[0][r][l] = s[r];
  }
  __syncthreads();
  if (w == 0) {
    #pragma unroll
    for (int r = 0; r < 16; r++) s[r] += red[0][r][l];
    #pragma unroll
    for (int off = 1; off < 32; off <<= 1)
      #pragma unroll
      for (int r = 0; r < 16; r++)
        s[r] += __shfl_xor(s[r], off);
    if (l31 == 0) {
      #pragma unroll
      for (int r = 0; r < 16; r++) {
        int k = k0 + (r & 3) + 8 * (r >> 2) + 4 * hi32;
        dinv[(size_t)bh * T_ + k] = 1.0f / s[r];
      }
    }
  }
}

// ---- V' = V * dinv, per-head transpose to (bh, HS, T) ----
__global__ __launch_bounds__(256) void transpose_v(
    const ushort_t* __restrict__ QKV, const float* __restrict__ dinv,
    ushort_t* __restrict__ Vt) {
  int t0 = blockIdx.x * 64;
  int bh = blockIdx.y; int b = bh >> 4, h = bh & 15;
  __shared__ ushort_t tile[64][65];
  int tid = threadIdx.x;
  #pragma unroll
  for (int i = 0; i < 16; i++) {
    int idx = i * 256 + tid;
    int tt = idx >> 6, dd = idx & 63;
    float v = bf2f(QKV[(size_t)(b * T_ + t0 + tt) * C3 + 2 * C_ + h * HS_ + dd]);
    tile[tt][dd] = f2bf(v * dinv[(size_t)bh * T_ + t0 + tt]);
  }
  __syncthreads();
  #pragma unroll
  for (int i = 0; i < 16; i++) {
    int idx = i * 256 + tid;
    int dd = idx >> 6, tt = idx & 63;
    Vt[((size_t)(bh * HS_ + dd)) * T_ + t0 + tt] = tile[tt][dd];
  }
}

// ---- PV: att[q,d] = sum_{k<=q} exp2(s') * V'[k,d]. 4 waves split k, LDS reduce ----
__global__ __launch_bounds__(256) void attn_pv(
    const ushort_t* __restrict__ QKV, const ushort_t* __restrict__ Vt,
    ushort_t* __restrict__ att) {
  int bh = blockIdx.x, tile = 63 - blockIdx.y;   // big first
  int b = bh >> 4, h = bh & 15;
  int t = threadIdx.x, w = t >> 6, l = t & 63, l31 = l & 31, hi32 = l >> 5;
  int q0 = tile * 32;
  __shared__ float red[2][32][64];   // 16KB
  const ushort_t* Qb = QKV + (size_t)b * T_ * C3 + h * HS_;
  const ushort_t* Kb = Qb + C_;
  const ushort_t* Vb = Vt + (size_t)bh * HS_ * T_;
  short8 qf[4];
  #pragma unroll
  for (int c = 0; c < 4; c++)
    qf[c] = *(const short8*)(Qb + (size_t)(q0 + l31) * C3 + c * 16 + hi32 * 8);
  f32x16 o0 = {}, o1 = {};
  int nkt = tile + 1;

  for (int kt = w; kt < nkt; kt += 4) {
    short8 ka[4], vf[4];
    #pragma unroll
    for (int c = 0; c < 4; c++)
      ka[c] = *(const short8*)(Kb + (size_t)(kt * 32 + l31) * C3 + c * 16 + hi32 * 8);
    #pragma unroll
    for (int c16 = 0; c16 < 2; c16++)
      #pragma unroll
      for (int dh = 0; dh < 2; dh++)
        vf[c16 * 2 + dh] = *(const short8*)(Vb +
            (size_t)(dh * 32 + l31) * T_ + kt * 32 + c16 * 16 + hi32 * 8);
    f32x16 sacc = {};
    #pragma unroll
    for (int c = 0; c < 4; c++) sacc = mfma32(ka[c], qf[c], sacc);
    float e[16];
    if (kt == tile) {            // diagonal: mask k <= q
      int q = q0 + l31;
      #pragma unroll
      for (int r = 0; r < 16; r++) {
        int k = kt * 32 + (r & 3) + 8 * (r >> 2) + 4 * hi32;
        e[r] = (k <= q) ? exp2f(sacc[r]) : 0.f;
      }
    } else {
      #pragma unroll
      for (int r = 0; r < 16; r++) e[r] = exp2f(sacc[r]);
    }
    unsigned u[8];
    #pragma unroll
    for (int j = 0; j < 8; j++) u[j] = pk2(e[2 * j], e[2 * j + 1]);
    pl32swap(u[0], u[2]); pl32swap(u[1], u[3]);
    pl32swap(u[4], u[6]); pl32swap(u[5], u[7]);
    short8 pa0 = mk8(u[0], u[1], u[2], u[3]);
    short8 pa1 = mk8(u[4], u[5], u[6], u[7]);
    o0 = mfma32(pa0, vf[0], o0);   // k 0..15,  d 0..31
    o1 = mfma32(pa0, vf[1], o1);   // k 0..15,  d 32..63
    o0 = mfma32(pa1, vf[2], o0);   // k 16..31, d 0..31
    o1 = mfma32(pa1, vf[3], o1);
  }

  // cross-wave tree reduce (o0 -> rows 0..15, o1 -> rows 16..31)
  if (w >= 2) {
    #pragma unroll
    for (int r = 0; r < 16; r++) {
      red[w - 2][r][l] = o0[r];
      red[w - 2][16 + r][l] = o1[r];
    }
  }
  __syncthreads();
  if (w < 2) {
    #pragma unroll
    for (int r = 0; r < 16; r++) {
      o0[r] += red[w][r][l];
      o1[r] += red[w][16 + r][l];
    }
  }
  __syncthreads();
  if (w == 1) {
    #pragma unroll
    for (int r = 0; r < 16; r++) {
      red[0][r][l] = o0[r];
      red[0][16 + r][l] = o1[r];
    }
  }
  __syncthreads();
  if (w == 0) {
    #pragma unroll
    for (int r = 0; r < 16; r++) {
      float v0 = o0[r] + red[0][r][l];
      float v1 = o1[r] + red[0][16 + r][l];
      int q = q0 + (r & 3) + 8 * (r >> 2) + 4 * hi32;
      size_t base = (size_t)(b * T_ + q) * C_ + h * HS_;
      att[base + l31]      = f2bf(v0);
      att[base + 32 + l31] = f2bf(v1);
    }
  }
}

extern "C" void kernel_launch(void* const* d_in, const int* in_sizes, int n_in,
                              void* d_out, int out_size, void* d_ws, size_t ws_size,
                              hipStream_t stream) {
  const float* x   = (const float*)d_in[0];
  const float* Wq  = (const float*)d_in[1];
  const float* bq  = (const float*)d_in[2];
  const float* Wk  = (const float*)d_in[3];
  const float* bk  = (const float*)d_in[4];
  const float* Wv  = (const float*)d_in[5];
  const float* bv  = (const float*)d_in[6];
  const float* Wo  = (const float*)d_in[7];
  const float* bo  = (const float*)d_in[8];
  const float* g1  = (const float*)d_in[9];
  const float* b1  = (const float*)d_in[10];
  const float* g2  = (const float*)d_in[11];
  const float* b2  = (const float*)d_in[12];
  const float* W1  = (const float*)d_in[13];
  const float* bf1 = (const float*)d_in[14];
  const float* W2  = (const float*)d_in[15];
  const float* bf2 = (const float*)d_in[16];
  float* out = (float*)d_out;

  char* base = (char*)d_ws;
  const size_t MB = 1 << 20;
  ushort_t* QKVb  = (ushort_t*)(base);            // 24MB
  ushort_t* hb    = (ushort_t*)(base + 24 * MB);  // 8MB: LN1 out -> att
  ushort_t* Vt    = (ushort_t*)(base + 32 * MB);  // 8MB: V' -> f1b
  float*    y     = (float*)   (base + 40 * MB);  // 16MB
  ushort_t* Wqkvt = (ushort_t*)(base + 56 * MB);  // 6MB
  ushort_t* Wot   = (ushort_t*)(base + 62 * MB);  // 2MB
  ushort_t* W1t   = (ushort_t*)(base + 64 * MB);  // 2MB
  ushort_t* W2t   = (ushort_t*)(base + 66 * MB);  // 2MB
  float*    bqkv  = (float*)   (base + 68 * MB);  // 12KB
  float*    dinv  = (float*)   (base + 68 * MB + 65536); // 256KB

  conv_wqkv3<<<12288, 256, 0, stream>>>(Wq, Wk, Wv, Wqkvt);
  conv_wt3  <<<12288, 256, 0, stream>>>(Wo, W1, W2, Wot);
  bias_cat  <<<12, 256, 0, stream>>>(bq, bk, bv, bqkv);

  ln_bf16<<<NROWS, 256, 0, stream>>>(x, g1, b1, hb);

  gemm128<<<dim3(C3 / 128, NROWS / 128), 256, 0, stream>>>(
      hb, Wqkvt, bqkv, QKVb, NROWS, C3, C_);

  attn_stats<<<dim3(32, 64), 256, 0, stream>>>(QKVb, dinv);
  transpose_v<<<dim3(T_ / 64, 32), 256, 0, stream>>>(QKVb, dinv, Vt);
  ushort_t* attb = hb;
  attn_pv<<<dim3(32, 64), 256, 0, stream>>>(QKVb, Vt, attb);

  dim3 g64(C_ / 64, NROWS / 128);
  gemm64<0,0,1><<<g64, 256, 0, stream>>>(attb, Wot, bo, x, y, NROWS, C_, C_);

  ushort_t* h2b = QKVb;
  ln_bf16<<<NROWS, 256, 0, stream>>>(y, g2, b2, h2b);
  ushort_t* f1b = Vt;
  gemm64<1,1,0><<<g64, 256, 0, stream>>>(h2b, W1t, bf1, nullptr, f1b, NROWS, C_, C_);
  gemm64<0,0,1><<<g64, 256, 0, stream>>>(f1b, W2t, bf2, y, out, NROWS, C_, C_);
}